// Round 1
// baseline (1327.473 us; speedup 1.0000x reference)
//
#include <hip/hip_runtime.h>

#define NN 100000
#define NE 3200000
#define F_IN 21
#define HID 64
#define EPS 1e-5f

// ---------------- CSR build ----------------

__global__ void k_count(const int* __restrict__ dst, int* __restrict__ cnt) {
    int i = blockIdx.x * blockDim.x + threadIdx.x;
    int stride = gridDim.x * blockDim.x;
    for (int e = i; e < NE; e += stride) atomicAdd(&cnt[dst[e]], 1);
}

__global__ void k_scan(const int* __restrict__ cnt, int* __restrict__ rowptr) {
    __shared__ int lds[1024];
    const int T = 1024;
    int t = threadIdx.x;
    const int chunk = (NN + T - 1) / T;
    int lo = t * chunk, hi = min(lo + chunk, NN);
    int s = 0;
    for (int i = lo; i < hi; ++i) s += cnt[i];
    lds[t] = s;
    __syncthreads();
    for (int off = 1; off < T; off <<= 1) {
        int v = (t >= off) ? lds[t - off] : 0;
        __syncthreads();
        lds[t] += v;
        __syncthreads();
    }
    int run = lds[t] - s;  // exclusive prefix
    for (int i = lo; i < hi; ++i) { rowptr[i] = run; run += cnt[i]; }
    if (t == 0) rowptr[NN] = NE;
}

__global__ void k_fill(const int* __restrict__ src, const int* __restrict__ dst,
                       const int* __restrict__ rowptr, int* __restrict__ cursor,
                       int* __restrict__ csr_src, int* __restrict__ csr_eid) {
    int i = blockIdx.x * blockDim.x + threadIdx.x;
    int stride = gridDim.x * blockDim.x;
    for (int e = i; e < NE; e += stride) {
        int d = dst[e];
        int pos = rowptr[d] + atomicAdd(&cursor[d], 1);
        csr_src[pos] = src[e];
        csr_eid[pos] = e;
    }
}

// ---------------- Layer 1: SAGE(x) + edge-encoder aggregation ----------------
// One wave per node; lane = output channel (0..63).

__global__ void __launch_bounds__(256, 4) k_layer1(
    const float* __restrict__ x, const float* __restrict__ edge_attr,
    const int* __restrict__ rowptr, const int* __restrict__ csr_src,
    const int* __restrict__ csr_eid,
    const float* __restrict__ We, const float* __restrict__ be,
    const float* __restrict__ W1l, const float* __restrict__ b1l,
    const float* __restrict__ W1r,
    float* __restrict__ h1pre, float* __restrict__ gsum, float* __restrict__ gsumsq) {
    int lane = threadIdx.x & 63;
    int wid = threadIdx.x >> 6;
    int gw = blockIdx.x * 4 + wid;
    int nw = gridDim.x * 4;

    float we0 = We[lane * 3], we1 = We[lane * 3 + 1], we2 = We[lane * 3 + 2];
    float beC = be[lane];
    float w1l[F_IN], w1r[F_IN];
#pragma unroll
    for (int k = 0; k < F_IN; ++k) {
        w1l[k] = W1l[lane * F_IN + k];
        w1r[k] = W1r[lane * F_IN + k];
    }
    float b1 = b1l[lane];

    float psum = 0.f, psumsq = 0.f;

    for (int n = gw; n < NN; n += nw) {
        int beg = rowptr[n], end = rowptr[n + 1];
        float accx = 0.f, acce = 0.f;
        for (int p0 = beg; p0 < end; p0 += 64) {
            int cntj = min(64, end - p0);
            int sL = 0;
            float a0L = 0.f, a1L = 0.f, a2L = 0.f;
            if (lane < cntj) {
                sL = csr_src[p0 + lane];
                int eL = csr_eid[p0 + lane];
                a0L = edge_attr[eL * 3];
                a1L = edge_attr[eL * 3 + 1];
                a2L = edge_attr[eL * 3 + 2];
            }
            for (int j = 0; j < cntj; ++j) {
                int s = __shfl(sL, j);
                float a0 = __shfl(a0L, j), a1 = __shfl(a1L, j), a2 = __shfl(a2L, j);
                float enc = fmaf(we0, a0, fmaf(we1, a1, fmaf(we2, a2, beC)));
                acce += fmaxf(enc, 0.f);
                if (lane < F_IN) accx += x[s * F_IN + lane];
            }
        }
        float invd = 1.f / fmaxf((float)(end - beg), 1.f);
        float aggv = accx * invd;
        float xv = (lane < F_IN) ? x[n * F_IN + lane] : 0.f;
        float h = b1 + acce;
#pragma unroll
        for (int k = 0; k < F_IN; ++k) {
            h = fmaf(w1l[k], __shfl(aggv, k), h);
            h = fmaf(w1r[k], __shfl(xv, k), h);
        }
        h1pre[n * HID + lane] = h;
        psum += h;
        psumsq += h * h;
    }

    __shared__ float bsum[HID], bsq[HID];
    if (threadIdx.x < HID) { bsum[threadIdx.x] = 0.f; bsq[threadIdx.x] = 0.f; }
    __syncthreads();
    atomicAdd(&bsum[lane], psum);
    atomicAdd(&bsq[lane], psumsq);
    __syncthreads();
    if (threadIdx.x < HID) {
        atomicAdd(&gsum[threadIdx.x], bsum[threadIdx.x]);
        atomicAdd(&gsumsq[threadIdx.x], bsq[threadIdx.x]);
    }
}

// ---------------- BN stats finalize ----------------

__global__ void k_bnstat(const float* __restrict__ gsum, const float* __restrict__ gsumsq,
                         const float* __restrict__ g, const float* __restrict__ beta,
                         float* __restrict__ scale, float* __restrict__ shift) {
    int c = threadIdx.x;
    if (c < HID) {
        float mu = gsum[c] * (1.f / (float)NN);
        float var = gsumsq[c] * (1.f / (float)NN) - mu * mu;
        float rstd = rsqrtf(var + EPS);
        float sc = rstd * g[c];
        scale[c] = sc;
        shift[c] = beta[c] - mu * sc;
    }
}

// ---------------- Layer 2: SAGE(relu(bn(h1))) ----------------
// BN+relu applied on the fly to gathered h1pre values.

__global__ void __launch_bounds__(256, 4) k_layer2(
    const float* __restrict__ h1pre,
    const int* __restrict__ rowptr, const int* __restrict__ csr_src,
    const float* __restrict__ W2l, const float* __restrict__ b2l,
    const float* __restrict__ W2r,
    const float* __restrict__ scale1, const float* __restrict__ shift1,
    float* __restrict__ h2pre, float* __restrict__ gsum, float* __restrict__ gsumsq) {
    __shared__ float ldsL[HID * HID];  // ldsL[k*64+c] = W2l[c][k]
    __shared__ float ldsR[HID * HID];
    for (int i = threadIdx.x; i < HID * HID; i += blockDim.x) {
        int k = i >> 6, c = i & 63;
        ldsL[i] = W2l[c * HID + k];
        ldsR[i] = W2r[c * HID + k];
    }
    __syncthreads();

    int lane = threadIdx.x & 63;
    int wid = threadIdx.x >> 6;
    int gw = blockIdx.x * 4 + wid;
    int nw = gridDim.x * 4;

    float sc = scale1[lane], sh = shift1[lane], b2 = b2l[lane];
    float psum = 0.f, psq = 0.f;

    for (int n = gw; n < NN; n += nw) {
        int beg = rowptr[n], end = rowptr[n + 1];
        float acc = 0.f;
        for (int p0 = beg; p0 < end; p0 += 64) {
            int cntj = min(64, end - p0);
            int sL = (lane < cntj) ? csr_src[p0 + lane] : 0;
            for (int j = 0; j < cntj; ++j) {
                int s = __shfl(sL, j);
                float v = h1pre[s * HID + lane];
                acc += fmaxf(fmaf(v, sc, sh), 0.f);
            }
        }
        float invd = 1.f / fmaxf((float)(end - beg), 1.f);
        float aggv = acc * invd;
        float own = fmaxf(fmaf(h1pre[n * HID + lane], sc, sh), 0.f);
        float h = b2;
#pragma unroll 16
        for (int k = 0; k < HID; ++k) {
            h = fmaf(ldsL[k * HID + lane], __shfl(aggv, k), h);
            h = fmaf(ldsR[k * HID + lane], __shfl(own, k), h);
        }
        h2pre[n * HID + lane] = h;
        psum += h;
        psq += h * h;
    }

    __shared__ float bsum[HID], bsq[HID];
    if (threadIdx.x < HID) { bsum[threadIdx.x] = 0.f; bsq[threadIdx.x] = 0.f; }
    __syncthreads();
    atomicAdd(&bsum[lane], psum);
    atomicAdd(&bsq[lane], psq);
    __syncthreads();
    if (threadIdx.x < HID) {
        atomicAdd(&gsum[threadIdx.x], bsum[threadIdx.x]);
        atomicAdd(&gsumsq[threadIdx.x], bsq[threadIdx.x]);
    }
}

// ---------------- Output head ----------------

__global__ void k_out(const float* __restrict__ h2pre,
                      const float* __restrict__ scale2, const float* __restrict__ shift2,
                      const float* __restrict__ Wc, const float* __restrict__ bc,
                      float* __restrict__ out) {
    int lane = threadIdx.x & 63;
    int wid = threadIdx.x >> 6;
    int gw = blockIdx.x * 4 + wid;
    int nw = gridDim.x * 4;
    float sc = scale2[lane], sh = shift2[lane];
    float wc0 = Wc[lane], wc1 = Wc[HID + lane];
    float b0 = bc[0], b1 = bc[1];
    for (int n = gw; n < NN; n += nw) {
        float v = fmaxf(fmaf(h2pre[n * HID + lane], sc, sh), 0.f);
        float r0 = v * wc0, r1 = v * wc1;
#pragma unroll
        for (int off = 32; off; off >>= 1) {
            r0 += __shfl_xor(r0, off);
            r1 += __shfl_xor(r1, off);
        }
        if (lane == 0) {
            out[n * 2] = r0 + b0;
            out[n * 2 + 1] = r1 + b1;
        }
    }
}

// ---------------- Host launcher ----------------

extern "C" void kernel_launch(void* const* d_in, const int* in_sizes, int n_in,
                              void* d_out, int out_size, void* d_ws, size_t ws_size,
                              hipStream_t stream) {
    const float* x = (const float*)d_in[0];
    const int* ei = (const int*)d_in[1];  // [2, E] int32: row0 = src, row1 = dst
    const float* edge_attr = (const float*)d_in[2];
    const float* We = (const float*)d_in[3];
    const float* be = (const float*)d_in[4];
    const float* W1l = (const float*)d_in[5];
    const float* b1l = (const float*)d_in[6];
    const float* W1r = (const float*)d_in[7];
    const float* W2l = (const float*)d_in[8];
    const float* b2l = (const float*)d_in[9];
    const float* W2r = (const float*)d_in[10];
    const float* g1 = (const float*)d_in[11];
    const float* beta1 = (const float*)d_in[12];
    const float* g2 = (const float*)d_in[13];
    const float* beta2 = (const float*)d_in[14];
    const float* Wc = (const float*)d_in[15];
    const float* bc = (const float*)d_in[16];
    float* out = (float*)d_out;

    const int* e_src = ei;
    const int* e_dst = ei + NE;

    char* ws = (char*)d_ws;
    size_t off = 0;
    auto alloc = [&](size_t bytes) {
        char* p = ws + off;
        off += (bytes + 255) & ~(size_t)255;
        return p;
    };
    int* rowptr = (int*)alloc((NN + 1) * sizeof(int));
    int* cnt = (int*)alloc(NN * sizeof(int));  // reused as cursor
    int* csr_src = (int*)alloc(NE * sizeof(int));
    int* csr_eid = (int*)alloc(NE * sizeof(int));
    float* h1pre = (float*)alloc((size_t)NN * HID * sizeof(float));
    float* h2pre = (float*)alloc((size_t)NN * HID * sizeof(float));
    float* stats = (float*)alloc(512 * sizeof(float));
    float* gsum1 = stats;
    float* gsq1 = stats + 64;
    float* gsum2 = stats + 128;
    float* gsq2 = stats + 192;
    float* scale1 = stats + 256;
    float* shift1 = stats + 320;
    float* scale2 = stats + 384;
    float* shift2 = stats + 448;

    hipMemsetAsync(cnt, 0, NN * sizeof(int), stream);
    hipMemsetAsync(stats, 0, 256 * sizeof(float), stream);  // zero gsum/gsq blocks

    k_count<<<4096, 256, 0, stream>>>(e_dst, cnt);
    k_scan<<<1, 1024, 0, stream>>>(cnt, rowptr);
    hipMemsetAsync(cnt, 0, NN * sizeof(int), stream);  // now the fill cursor
    k_fill<<<4096, 256, 0, stream>>>(e_src, e_dst, rowptr, cnt, csr_src, csr_eid);

    k_layer1<<<2048, 256, 0, stream>>>(x, edge_attr, rowptr, csr_src, csr_eid,
                                       We, be, W1l, b1l, W1r, h1pre, gsum1, gsq1);
    k_bnstat<<<1, 64, 0, stream>>>(gsum1, gsq1, g1, beta1, scale1, shift1);
    k_layer2<<<2048, 256, 0, stream>>>(h1pre, rowptr, csr_src, W2l, b2l, W2r,
                                       scale1, shift1, h2pre, gsum2, gsq2);
    k_bnstat<<<1, 64, 0, stream>>>(gsum2, gsq2, g2, beta2, scale2, shift2);
    k_out<<<1024, 256, 0, stream>>>(h2pre, scale2, shift2, Wc, bc, out);
}

// Round 3
// 1117.632 us; speedup vs baseline: 1.1878x; 1.1878x over previous
//
#include <hip/hip_runtime.h>

#define NN 100000
#define NE 3200000
#define F_IN 21
#define HID 64
#define EPS 1e-5f

// ---------------- CSR build ----------------

__global__ void k_count(const int* __restrict__ dst, int* __restrict__ cnt,
                        int* __restrict__ slot) {
    int i = blockIdx.x * blockDim.x + threadIdx.x;
    int st = gridDim.x * blockDim.x;
    for (int e = i; e < NE; e += st) slot[e] = atomicAdd(&cnt[dst[e]], 1);
}

__global__ void k_scan(const int* __restrict__ cnt, int* __restrict__ rowptr) {
    __shared__ int lds[1024];
    int t = threadIdx.x;
    const int CH = 100;  // 1000 threads x 100 = 100000
    int lo = t * CH;
    int s = 0;
    if (lo < NN) {
        const int4* p = (const int4*)(cnt + lo);
#pragma unroll
        for (int i = 0; i < CH / 4; ++i) { int4 v = p[i]; s += v.x + v.y + v.z + v.w; }
    }
    lds[t] = s;
    __syncthreads();
    for (int off = 1; off < 1024; off <<= 1) {
        int v = (t >= off) ? lds[t - off] : 0;
        __syncthreads();
        lds[t] += v;
        __syncthreads();
    }
    if (lo < NN) {
        int run = lds[t] - s;  // exclusive prefix
        for (int i = lo; i < lo + CH; ++i) { rowptr[i] = run; run += cnt[i]; }
    }
    if (t == 0) rowptr[NN] = NE;
}

__global__ void k_fill(const int* __restrict__ src, const int* __restrict__ dst,
                       const float* __restrict__ eattr,
                       const int* __restrict__ rowptr, const int* __restrict__ slot,
                       int* __restrict__ csr_src, float* __restrict__ csr_attr) {
    int i = blockIdx.x * blockDim.x + threadIdx.x;
    int st = gridDim.x * blockDim.x;
    for (int e = i; e < NE; e += st) {
        int d = dst[e];
        int pos = rowptr[d] + slot[e];
        csr_src[pos] = src[e];
        size_t pb = (size_t)pos * 3;
        size_t eb = (size_t)e * 3;
        csr_attr[pb] = eattr[eb];
        csr_attr[pb + 1] = eattr[eb + 1];
        csr_attr[pb + 2] = eattr[eb + 2];
    }
}

// ---------------- pre1: yl = x@W1l.T ; own(h1 init) = x@W1r.T + b1 ----------------

__global__ void __launch_bounds__(256, 4) k_pre1(
    const float* __restrict__ x, const float* __restrict__ W1l,
    const float* __restrict__ b1l, const float* __restrict__ W1r,
    float* __restrict__ yl, float* __restrict__ own) {
    int lane = threadIdx.x & 63;
    int gw = blockIdx.x * 4 + (threadIdx.x >> 6);
    int nw = gridDim.x * 4;
    float wl[F_IN], wr[F_IN];
#pragma unroll
    for (int k = 0; k < F_IN; ++k) {
        wl[k] = W1l[lane * F_IN + k];
        wr[k] = W1r[lane * F_IN + k];
    }
    float b = b1l[lane];
    for (int n = gw; n < NN; n += nw) {
        float xv = (lane < F_IN) ? x[(size_t)n * F_IN + lane] : 0.f;
        float sy = 0.f, so = b;
#pragma unroll
        for (int k = 0; k < F_IN; ++k) {
            float xk = __shfl(xv, k);
            sy = fmaf(wl[k], xk, sy);
            so = fmaf(wr[k], xk, so);
        }
        yl[(size_t)n * HID + lane] = sy;
        own[(size_t)n * HID + lane] = so;
    }
}

// ---------------- gather1: h1 = own + mean(yl[src]) + sum(relu(We@attr+be)) ----------------
// wave per node; 4 groups x 16 lanes; lane holds channel quad 4*c4..+3

#define GRED(v) { v += __shfl_xor(v, 16); v += __shfl_xor(v, 32); }

__global__ void __launch_bounds__(256, 4) k_gather1(
    const float* __restrict__ yl, const float* __restrict__ csr_attr,
    const int* __restrict__ csr_src, const int* __restrict__ rowptr,
    const float* __restrict__ We, const float* __restrict__ be,
    float* __restrict__ H1, float* __restrict__ gsum, float* __restrict__ gsq) {
    int lane = threadIdx.x & 63;
    int g = lane >> 4, c4 = lane & 15;
    int gw = blockIdx.x * 4 + (threadIdx.x >> 6);
    int nw = gridDim.x * 4;

    float wa0 = We[(4 * c4 + 0) * 3], wb0 = We[(4 * c4 + 0) * 3 + 1], wc0 = We[(4 * c4 + 0) * 3 + 2];
    float wa1 = We[(4 * c4 + 1) * 3], wb1 = We[(4 * c4 + 1) * 3 + 1], wc1 = We[(4 * c4 + 1) * 3 + 2];
    float wa2 = We[(4 * c4 + 2) * 3], wb2 = We[(4 * c4 + 2) * 3 + 1], wc2 = We[(4 * c4 + 2) * 3 + 2];
    float wa3 = We[(4 * c4 + 3) * 3], wb3 = We[(4 * c4 + 3) * 3 + 1], wc3 = We[(4 * c4 + 3) * 3 + 2];
    float bq0 = be[4 * c4 + 0], bq1 = be[4 * c4 + 1], bq2 = be[4 * c4 + 2], bq3 = be[4 * c4 + 3];

    float ps0 = 0, ps1 = 0, ps2 = 0, ps3 = 0, pq0 = 0, pq1 = 0, pq2 = 0, pq3 = 0;

    for (int n = gw; n < NN; n += nw) {
        int beg = rowptr[n], end = rowptr[n + 1];
        float aY0 = 0, aY1 = 0, aY2 = 0, aY3 = 0;
        float aE0 = 0, aE1 = 0, aE2 = 0, aE3 = 0;
        for (int p0 = beg; p0 < end; p0 += 64) {
            int cntj = min(64, end - p0);
            int sL = 0;
            float a0L = 0.f, a1L = 0.f, a2L = 0.f;
            if (lane < cntj) {
                sL = csr_src[p0 + lane];
                const float* ap = csr_attr + (size_t)(p0 + lane) * 3;
                a0L = ap[0]; a1L = ap[1]; a2L = ap[2];
            }
            int jm = (cntj + 3) >> 2;
#pragma unroll 2
            for (int j = 0; j < jm; ++j) {
                int idx = j * 4 + g;
                int s = __shfl(sL, idx);
                float a0 = __shfl(a0L, idx);
                float a1 = __shfl(a1L, idx);
                float a2 = __shfl(a2L, idx);
                float m = (idx < cntj) ? 1.f : 0.f;
                const float4 y = *(const float4*)(yl + (size_t)s * HID + 4 * c4);
                aY0 = fmaf(y.x, m, aY0);
                aY1 = fmaf(y.y, m, aY1);
                aY2 = fmaf(y.z, m, aY2);
                aY3 = fmaf(y.w, m, aY3);
                float e0 = fmaf(wa0, a0, fmaf(wb0, a1, fmaf(wc0, a2, bq0)));
                float e1 = fmaf(wa1, a0, fmaf(wb1, a1, fmaf(wc1, a2, bq1)));
                float e2 = fmaf(wa2, a0, fmaf(wb2, a1, fmaf(wc2, a2, bq2)));
                float e3 = fmaf(wa3, a0, fmaf(wb3, a1, fmaf(wc3, a2, bq3)));
                aE0 = fmaf(fmaxf(e0, 0.f), m, aE0);
                aE1 = fmaf(fmaxf(e1, 0.f), m, aE1);
                aE2 = fmaf(fmaxf(e2, 0.f), m, aE2);
                aE3 = fmaf(fmaxf(e3, 0.f), m, aE3);
            }
        }
        GRED(aY0) GRED(aY1) GRED(aY2) GRED(aY3)
        GRED(aE0) GRED(aE1) GRED(aE2) GRED(aE3)
        if (g == 0) {
            float invd = 1.f / fmaxf((float)(end - beg), 1.f);
            const float4 own = *(const float4*)(H1 + (size_t)n * HID + 4 * c4);
            float h0 = fmaf(aY0, invd, own.x) + aE0;
            float h1v = fmaf(aY1, invd, own.y) + aE1;
            float h2v = fmaf(aY2, invd, own.z) + aE2;
            float h3v = fmaf(aY3, invd, own.w) + aE3;
            float4 hv = {h0, h1v, h2v, h3v};
            *(float4*)(H1 + (size_t)n * HID + 4 * c4) = hv;
            ps0 += h0; ps1 += h1v; ps2 += h2v; ps3 += h3v;
            pq0 += h0 * h0; pq1 += h1v * h1v; pq2 += h2v * h2v; pq3 += h3v * h3v;
        }
    }
    __shared__ float bs[HID], bq[HID];
    if (threadIdx.x < HID) { bs[threadIdx.x] = 0.f; bq[threadIdx.x] = 0.f; }
    __syncthreads();
    if (g == 0) {
        atomicAdd(&bs[4 * c4 + 0], ps0); atomicAdd(&bq[4 * c4 + 0], pq0);
        atomicAdd(&bs[4 * c4 + 1], ps1); atomicAdd(&bq[4 * c4 + 1], pq1);
        atomicAdd(&bs[4 * c4 + 2], ps2); atomicAdd(&bq[4 * c4 + 2], pq2);
        atomicAdd(&bs[4 * c4 + 3], ps3); atomicAdd(&bq[4 * c4 + 3], pq3);
    }
    __syncthreads();
    if (threadIdx.x < HID) {
        atomicAdd(&gsum[threadIdx.x], bs[threadIdx.x]);
        atomicAdd(&gsq[threadIdx.x], bq[threadIdx.x]);
    }
}

// ---------------- BN finalize ----------------

__global__ void k_bnstat(const float* __restrict__ gsum, const float* __restrict__ gsq,
                         const float* __restrict__ g, const float* __restrict__ beta,
                         float* __restrict__ scale, float* __restrict__ shift) {
    int c = threadIdx.x;
    if (c < HID) {
        float mu = gsum[c] * (1.f / (float)NN);
        float var = gsq[c] * (1.f / (float)NN) - mu * mu;
        float rstd = rsqrtf(var + EPS);
        float sc = rstd * g[c];
        scale[c] = sc;
        shift[c] = beta[c] - mu * sc;
    }
}

// ---------------- pre2: act=relu(bn(h1)); U=act@W2l.T; Z=act@W2r.T+b2 ----------------
// wave handles 8 nodes per iter (2 per group), W staged transposed in LDS.

__global__ void __launch_bounds__(256, 4) k_pre2(
    const float* __restrict__ H1, const float* __restrict__ W2l,
    const float* __restrict__ W2r, const float* __restrict__ b2l,
    const float* __restrict__ sc1, const float* __restrict__ sh1,
    float* __restrict__ U, float* __restrict__ Z) {
    __shared__ float ldsL[HID * HID];  // [k][c]
    __shared__ float ldsR[HID * HID];
    for (int i = threadIdx.x; i < HID * HID; i += blockDim.x) {
        int k = i >> 6, c = i & 63;
        ldsL[i] = W2l[c * HID + k];
        ldsR[i] = W2r[c * HID + k];
    }
    __syncthreads();
    int lane = threadIdx.x & 63;
    int g = lane >> 4, c4 = lane & 15;
    int wv = blockIdx.x * 4 + (threadIdx.x >> 6);
    int nw = gridDim.x * 4;
    float4 sc = *(const float4*)(sc1 + 4 * c4);
    float4 sh = *(const float4*)(sh1 + 4 * c4);
    float4 bb = *(const float4*)(b2l + 4 * c4);
    for (int t = wv; t < NN / 8; t += nw) {
        int nA = t * 8 + 2 * g;
        float4 hA = *(const float4*)(H1 + (size_t)nA * HID + 4 * c4);
        float4 hB = *(const float4*)(H1 + (size_t)(nA + 1) * HID + 4 * c4);
        float4 aA, aB;
        aA.x = fmaxf(fmaf(hA.x, sc.x, sh.x), 0.f);
        aA.y = fmaxf(fmaf(hA.y, sc.y, sh.y), 0.f);
        aA.z = fmaxf(fmaf(hA.z, sc.z, sh.z), 0.f);
        aA.w = fmaxf(fmaf(hA.w, sc.w, sh.w), 0.f);
        aB.x = fmaxf(fmaf(hB.x, sc.x, sh.x), 0.f);
        aB.y = fmaxf(fmaf(hB.y, sc.y, sh.y), 0.f);
        aB.z = fmaxf(fmaf(hB.z, sc.z, sh.z), 0.f);
        aB.w = fmaxf(fmaf(hB.w, sc.w, sh.w), 0.f);
        float uA0 = 0, uA1 = 0, uA2 = 0, uA3 = 0, uB0 = 0, uB1 = 0, uB2 = 0, uB3 = 0;
        float zA0 = 0, zA1 = 0, zA2 = 0, zA3 = 0, zB0 = 0, zB1 = 0, zB2 = 0, zB3 = 0;
#pragma unroll
        for (int k = 0; k < HID; ++k) {
            int srcl = (g << 4) | (k >> 2);
            float cA = (k & 3) == 0 ? aA.x : (k & 3) == 1 ? aA.y : (k & 3) == 2 ? aA.z : aA.w;
            float cB = (k & 3) == 0 ? aB.x : (k & 3) == 1 ? aB.y : (k & 3) == 2 ? aB.z : aB.w;
            float vA = __shfl(cA, srcl);
            float vB = __shfl(cB, srcl);
            const float4 wl = *(const float4*)(ldsL + k * HID + 4 * c4);
            const float4 wr = *(const float4*)(ldsR + k * HID + 4 * c4);
            uA0 = fmaf(wl.x, vA, uA0); uA1 = fmaf(wl.y, vA, uA1);
            uA2 = fmaf(wl.z, vA, uA2); uA3 = fmaf(wl.w, vA, uA3);
            uB0 = fmaf(wl.x, vB, uB0); uB1 = fmaf(wl.y, vB, uB1);
            uB2 = fmaf(wl.z, vB, uB2); uB3 = fmaf(wl.w, vB, uB3);
            zA0 = fmaf(wr.x, vA, zA0); zA1 = fmaf(wr.y, vA, zA1);
            zA2 = fmaf(wr.z, vA, zA2); zA3 = fmaf(wr.w, vA, zA3);
            zB0 = fmaf(wr.x, vB, zB0); zB1 = fmaf(wr.y, vB, zB1);
            zB2 = fmaf(wr.z, vB, zB2); zB3 = fmaf(wr.w, vB, zB3);
        }
        float4 o;
        o.x = uA0; o.y = uA1; o.z = uA2; o.w = uA3;
        *(float4*)(U + (size_t)nA * HID + 4 * c4) = o;
        o.x = uB0; o.y = uB1; o.z = uB2; o.w = uB3;
        *(float4*)(U + (size_t)(nA + 1) * HID + 4 * c4) = o;
        o.x = zA0 + bb.x; o.y = zA1 + bb.y; o.z = zA2 + bb.z; o.w = zA3 + bb.w;
        *(float4*)(Z + (size_t)nA * HID + 4 * c4) = o;
        o.x = zB0 + bb.x; o.y = zB1 + bb.y; o.z = zB2 + bb.z; o.w = zB3 + bb.w;
        *(float4*)(Z + (size_t)(nA + 1) * HID + 4 * c4) = o;
    }
}

// ---------------- gather2: h2 = mean(U[src]) + Z  (in place over Z) ----------------

__global__ void __launch_bounds__(256, 8) k_gather2(
    const float* __restrict__ U, const int* __restrict__ csr_src,
    const int* __restrict__ rowptr, float* __restrict__ ZH,
    float* __restrict__ gsum, float* __restrict__ gsq) {
    int lane = threadIdx.x & 63;
    int g = lane >> 4, c4 = lane & 15;
    int gw = blockIdx.x * 4 + (threadIdx.x >> 6);
    int nw = gridDim.x * 4;
    float ps0 = 0, ps1 = 0, ps2 = 0, ps3 = 0, pq0 = 0, pq1 = 0, pq2 = 0, pq3 = 0;

    for (int n = gw; n < NN; n += nw) {
        int beg = rowptr[n], end = rowptr[n + 1];
        float a0 = 0, a1 = 0, a2 = 0, a3 = 0;
        for (int p0 = beg; p0 < end; p0 += 64) {
            int cntj = min(64, end - p0);
            int sL = (lane < cntj) ? csr_src[p0 + lane] : 0;
            int jm = (cntj + 3) >> 2;
#pragma unroll 2
            for (int j = 0; j < jm; ++j) {
                int idx = j * 4 + g;
                int s = __shfl(sL, idx);
                float m = (idx < cntj) ? 1.f : 0.f;
                const float4 y = *(const float4*)(U + (size_t)s * HID + 4 * c4);
                a0 = fmaf(y.x, m, a0);
                a1 = fmaf(y.y, m, a1);
                a2 = fmaf(y.z, m, a2);
                a3 = fmaf(y.w, m, a3);
            }
        }
        GRED(a0) GRED(a1) GRED(a2) GRED(a3)
        if (g == 0) {
            float invd = 1.f / fmaxf((float)(end - beg), 1.f);
            float4 z = *(const float4*)(ZH + (size_t)n * HID + 4 * c4);
            float h0 = fmaf(a0, invd, z.x);
            float h1v = fmaf(a1, invd, z.y);
            float h2v = fmaf(a2, invd, z.z);
            float h3v = fmaf(a3, invd, z.w);
            float4 hv = {h0, h1v, h2v, h3v};
            *(float4*)(ZH + (size_t)n * HID + 4 * c4) = hv;
            ps0 += h0; ps1 += h1v; ps2 += h2v; ps3 += h3v;
            pq0 += h0 * h0; pq1 += h1v * h1v; pq2 += h2v * h2v; pq3 += h3v * h3v;
        }
    }
    __shared__ float bs[HID], bq[HID];
    if (threadIdx.x < HID) { bs[threadIdx.x] = 0.f; bq[threadIdx.x] = 0.f; }
    __syncthreads();
    if (g == 0) {
        atomicAdd(&bs[4 * c4 + 0], ps0); atomicAdd(&bq[4 * c4 + 0], pq0);
        atomicAdd(&bs[4 * c4 + 1], ps1); atomicAdd(&bq[4 * c4 + 1], pq1);
        atomicAdd(&bs[4 * c4 + 2], ps2); atomicAdd(&bq[4 * c4 + 2], pq2);
        atomicAdd(&bs[4 * c4 + 3], ps3); atomicAdd(&bq[4 * c4 + 3], pq3);
    }
    __syncthreads();
    if (threadIdx.x < HID) {
        atomicAdd(&gsum[threadIdx.x], bs[threadIdx.x]);
        atomicAdd(&gsq[threadIdx.x], bq[threadIdx.x]);
    }
}

// ---------------- output head ----------------

__global__ void k_out(const float* __restrict__ H2,
                      const float* __restrict__ sc2, const float* __restrict__ sh2,
                      const float* __restrict__ Wc, const float* __restrict__ bc,
                      float* __restrict__ out) {
    int lane = threadIdx.x & 63;
    int g = lane >> 4, c4 = lane & 15;
    int wv = blockIdx.x * 4 + (threadIdx.x >> 6);
    int nw = gridDim.x * 4;
    float4 sc = *(const float4*)(sc2 + 4 * c4);
    float4 sh = *(const float4*)(sh2 + 4 * c4);
    float4 w0 = *(const float4*)(Wc + 4 * c4);
    float4 w1 = *(const float4*)(Wc + HID + 4 * c4);
    float b0 = bc[0], b1 = bc[1];
    for (int t = wv; t < NN / 4; t += nw) {
        int n = t * 4 + g;
        float4 h = *(const float4*)(H2 + (size_t)n * HID + 4 * c4);
        float vx = fmaxf(fmaf(h.x, sc.x, sh.x), 0.f);
        float vy = fmaxf(fmaf(h.y, sc.y, sh.y), 0.f);
        float vz = fmaxf(fmaf(h.z, sc.z, sh.z), 0.f);
        float vw = fmaxf(fmaf(h.w, sc.w, sh.w), 0.f);
        float r0 = vx * w0.x + vy * w0.y + vz * w0.z + vw * w0.w;
        float r1 = vx * w1.x + vy * w1.y + vz * w1.z + vw * w1.w;
#pragma unroll
        for (int off = 1; off <= 8; off <<= 1) {
            r0 += __shfl_xor(r0, off);
            r1 += __shfl_xor(r1, off);
        }
        if (c4 == 0) {
            out[(size_t)n * 2] = r0 + b0;
            out[(size_t)n * 2 + 1] = r1 + b1;
        }
    }
}

// ---------------- host launcher ----------------

extern "C" void kernel_launch(void* const* d_in, const int* in_sizes, int n_in,
                              void* d_out, int out_size, void* d_ws, size_t ws_size,
                              hipStream_t stream) {
    const float* x = (const float*)d_in[0];
    const int* ei = (const int*)d_in[1];
    const float* eattr = (const float*)d_in[2];
    const float* We = (const float*)d_in[3];
    const float* be = (const float*)d_in[4];
    const float* W1l = (const float*)d_in[5];
    const float* b1l = (const float*)d_in[6];
    const float* W1r = (const float*)d_in[7];
    const float* W2l = (const float*)d_in[8];
    const float* b2l = (const float*)d_in[9];
    const float* W2r = (const float*)d_in[10];
    const float* g1 = (const float*)d_in[11];
    const float* beta1 = (const float*)d_in[12];
    const float* g2 = (const float*)d_in[13];
    const float* beta2 = (const float*)d_in[14];
    const float* Wc = (const float*)d_in[15];
    const float* bc = (const float*)d_in[16];
    float* out = (float*)d_out;

    const int* e_src = ei;
    const int* e_dst = ei + NE;

    char* ws = (char*)d_ws;
    size_t off = 0;
    auto alloc = [&](size_t b) {
        char* p = ws + off;
        off += (b + 255) & ~(size_t)255;
        return p;
    };
    int* rowptr = (int*)alloc((NN + 1) * sizeof(int));
    int* cnt = (int*)alloc(NN * sizeof(int));
    int* csr_src = (int*)alloc((size_t)NE * sizeof(int));
    float* csr_attr = (float*)alloc((size_t)NE * 3 * sizeof(float));  // -> U after gather1
    float* bufY = (float*)alloc((size_t)NN * HID * sizeof(float));    // yl -> Z -> h2
    float* bufH = (float*)alloc((size_t)NN * HID * sizeof(float));    // slot -> own/h1
    float* stats = (float*)alloc(512 * sizeof(float));
    float* gsum1 = stats, *gsq1 = stats + 64, *gsum2 = stats + 128, *gsq2 = stats + 192;
    float* scale1 = stats + 256, *shift1 = stats + 320;
    float* scale2 = stats + 384, *shift2 = stats + 448;

    int* slot = (int*)bufH;     // alias: dead before h1 is written
    float* H1 = bufH;
    float* U = csr_attr;        // alias: attrs dead after gather1
    float* Z = bufY;            // alias: yl dead after gather1; h2 in place over Z

    hipMemsetAsync(cnt, 0, NN * sizeof(int), stream);
    hipMemsetAsync(stats, 0, 256 * sizeof(float), stream);

    k_count<<<2048, 256, 0, stream>>>(e_dst, cnt, slot);
    k_scan<<<1, 1024, 0, stream>>>(cnt, rowptr);
    k_fill<<<2048, 256, 0, stream>>>(e_src, e_dst, eattr, rowptr, slot, csr_src, csr_attr);
    k_pre1<<<2048, 256, 0, stream>>>(x, W1l, b1l, W1r, bufY, H1);
    k_gather1<<<2048, 256, 0, stream>>>(bufY, csr_attr, csr_src, rowptr, We, be,
                                        H1, gsum1, gsq1);
    k_bnstat<<<1, 64, 0, stream>>>(gsum1, gsq1, g1, beta1, scale1, shift1);
    k_pre2<<<1024, 256, 0, stream>>>(H1, W2l, W2r, b2l, scale1, shift1, U, Z);
    k_gather2<<<2048, 256, 0, stream>>>(U, csr_src, rowptr, Z, gsum2, gsq2);
    k_bnstat<<<1, 64, 0, stream>>>(gsum2, gsq2, g2, beta2, scale2, shift2);
    k_out<<<512, 256, 0, stream>>>(Z, scale2, shift2, Wc, bc, out);
}